// Round 9
// baseline (183.568 us; speedup 1.0000x reference)
//
#include <hip/hip_runtime.h>
#include <hip/hip_bf16.h>

typedef float f32x4 __attribute__((ext_vector_type(4)));
typedef short s16x8 __attribute__((ext_vector_type(8)));
typedef short s16x4 __attribute__((ext_vector_type(4)));

#define N_NODES 768
#define NODE_DIM_ 256
#define HDIM 64
#define EDIM 128
#define CTILES 48                       // 768 / 16
#define TILES_TOTAL (N_NODES * CTILES)  // 36864

// DIAGNOSTIC ROUND: tile loop repeated 3x inside one dispatch (idempotent,
// identical values stored each pass) so the edge dispatch exceeds the harness
// poison-fill durations (~174us) and shows up in the top-5 counter table.
#define REPS 3

static __device__ __forceinline__ short f2bf(float f) {
    __hip_bfloat16 h = __float2bfloat16(f);
    return __builtin_bit_cast(short, h);
}
static __device__ __forceinline__ float bf2f(short h) {
    unsigned u = ((unsigned)(unsigned short)h) << 16;
    return __builtin_bit_cast(float, u);
}

// ---------------- Kernel 1: n_i = x@Wi + bi, n_j = x@Wj + bj ----------------
__global__ __launch_bounds__(256) void proj_kernel(
        const float* __restrict__ x,
        const float* __restrict__ Wi, const float* __restrict__ bi,
        const float* __restrict__ Wj, const float* __restrict__ bj,
        float* __restrict__ NI, float* __restrict__ NJ) {
    int row  = blockIdx.x * 4 + (threadIdx.x >> 6);
    int lane = threadIdx.x & 63;
    float ai = bi[lane];
    float aj = bj[lane];
    const float* xr = x + row * NODE_DIM_;
#pragma unroll 8
    for (int k = 0; k < NODE_DIM_; ++k) {
        float xv = xr[k];
        ai = fmaf(xv, Wi[k * HDIM + lane], ai);
        aj = fmaf(xv, Wj[k * HDIM + lane], aj);
    }
    NI[row * HDIM + lane] = ai;
    NJ[row * HDIM + lane] = aj;
}

// ------- Kernel 2: R8 body (split-bf16, blocked tiles, XCD swizzle) x REPS -------
__global__ __launch_bounds__(256) void edge_kernel(
        const float* __restrict__ NI, const float* __restrict__ NJ,
        const float* __restrict__ lng, const float* __restrict__ lnb,
        const float* __restrict__ W1, const float* __restrict__ b1,
        const float* __restrict__ W2, const float* __restrict__ b2,
        float* __restrict__ out) {
    __shared__ short W1L[4096];      // 8 KB
    __shared__ short W2L[8192];      // 16 KB
    __shared__ short TLh[4][1024];   // per-wave t-hi tile, swizzled
    __shared__ short TLl[4][1024];   // per-wave t-lo tile

    for (int idx = threadIdx.x; idx < 4096; idx += 256) {
        int k = idx >> 6, n = idx & 63;
        W1L[(k >> 3) * 512 + n * 8 + (k & 7)] = f2bf(W1[idx]);
    }
    for (int idx = threadIdx.x; idx < 8192; idx += 256) {
        int k = idx >> 7, n = idx & 127;
        W2L[(k >> 3) * 1024 + n * 8 + (k & 7)] = f2bf(W2[idx]);
    }
    __syncthreads();

    const int wave = threadIdx.x >> 6;
    const int lane = threadIdx.x & 63;
    const int l15  = lane & 15;
    const int hi   = lane >> 4;
    const int swz  = (l15 & 7) << 4;

    float gl[8], gh[8], bl[8], bh[8];
#pragma unroll
    for (int j = 0; j < 8; ++j) {
        gl[j] = lng[hi * 8 + j];      gh[j] = lng[32 + hi * 8 + j];
        bl[j] = lnb[hi * 8 + j];      bh[j] = lnb[32 + hi * 8 + j];
    }
    float b1v[16];
#pragma unroll
    for (int nt = 0; nt < 4; ++nt)
#pragma unroll
        for (int r = 0; r < 4; ++r)
            b1v[nt * 4 + r] = b1[nt * 16 + hi * 4 + r];
    float b2v[8];
#pragma unroll
    for (int nt = 0; nt < 8; ++nt)
        b2v[nt] = b2[nt * 16 + l15];

    char* tlh = (char*)&TLh[wave][0];
    char* tll = (char*)&TLl[wave][0];

    const int swzb = (blockIdx.x & 7) * 288 + (blockIdx.x >> 3);
    const int wid  = swzb * 4 + wave;
    const int t0   = wid * 4;

#pragma unroll 1
    for (int rep = 0; rep < REPS; ++rep) {
#pragma unroll 1
    for (int k4 = 0; k4 < 4; ++k4) {
        const int t  = t0 + k4;
        const int a  = t / CTILES;
        const int c0 = (t - a * CTILES) * 16;

        const float* nip = NI + (c0 + l15) * HDIM + hi * 8;
        const float* njp = NJ + a * HDIM + hi * 8;
        float v[16];
#pragma unroll
        for (int j = 0; j < 8; ++j) {
            v[j]     = nip[j]      + njp[j];
            v[8 + j] = nip[32 + j] + njp[32 + j];
        }
        float s = 0.f, ss = 0.f;
#pragma unroll
        for (int j = 0; j < 16; ++j) { s += v[j]; ss = fmaf(v[j], v[j], ss); }
        s += __shfl_xor(s, 16);  ss += __shfl_xor(ss, 16);
        s += __shfl_xor(s, 32);  ss += __shfl_xor(ss, 32);
        float mu   = s * (1.f / 64.f);
        float var  = ss * (1.f / 64.f) - mu * mu;
        float rstd = rsqrtf(var + 1e-5f);

        s16x8 hf0h, hf0l, hf1h, hf1l;
#pragma unroll
        for (int j = 0; j < 8; ++j) {
            float h0 = fmaf((v[j]     - mu) * rstd, gl[j], bl[j]);
            float h1 = fmaf((v[8 + j] - mu) * rstd, gh[j], bh[j]);
            short a0 = f2bf(h0);
            short a1 = f2bf(h1);
            hf0h[j] = a0;  hf0l[j] = f2bf(h0 - bf2f(a0));
            hf1h[j] = a1;  hf1l[j] = f2bf(h1 - bf2f(a1));
        }

#pragma unroll
        for (int nt = 0; nt < 4; ++nt) {
            f32x4 acc = {0.f, 0.f, 0.f, 0.f};
            s16x8 w0 = *(const s16x8*)&W1L[(0 + hi) * 512 + (nt * 16 + l15) * 8];
            s16x8 w1 = *(const s16x8*)&W1L[(4 + hi) * 512 + (nt * 16 + l15) * 8];
            acc = __builtin_amdgcn_mfma_f32_16x16x32_bf16(w0, hf0h, acc, 0, 0, 0);
            acc = __builtin_amdgcn_mfma_f32_16x16x32_bf16(w1, hf1h, acc, 0, 0, 0);
            acc = __builtin_amdgcn_mfma_f32_16x16x32_bf16(w0, hf0l, acc, 0, 0, 0);
            acc = __builtin_amdgcn_mfma_f32_16x16x32_bf16(w1, hf1l, acc, 0, 0, 0);
            s16x4 tvh, tvl;
#pragma unroll
            for (int r = 0; r < 4; ++r) {
                float tt = fmaxf(acc[r] + b1v[nt * 4 + r], 0.f);
                short th = f2bf(tt);
                tvh[r] = th;
                tvl[r] = f2bf(tt - bf2f(th));
            }
            int wb = (l15 * 128 + (nt * 16 + hi * 4) * 2) ^ swz;
            *(s16x4*)(tlh + wb) = tvh;
            *(s16x4*)(tll + wb) = tvl;
        }

        int rb0 = (l15 * 128 + hi * 16) ^ swz;
        int rb1 = (l15 * 128 + hi * 16 + 64) ^ swz;
        s16x8 tf0h = *(const s16x8*)(tlh + rb0);
        s16x8 tf1h = *(const s16x8*)(tlh + rb1);
        s16x8 tf0l = *(const s16x8*)(tll + rb0);
        s16x8 tf1l = *(const s16x8*)(tll + rb1);

        float* op = out + ((size_t)(a * N_NODES + c0 + hi * 4)) * EDIM + l15;
#pragma unroll
        for (int nt = 0; nt < 8; ++nt) {
            f32x4 acc = {0.f, 0.f, 0.f, 0.f};
            s16x8 w0 = *(const s16x8*)&W2L[(0 + hi) * 1024 + (nt * 16 + l15) * 8];
            s16x8 w1 = *(const s16x8*)&W2L[(4 + hi) * 1024 + (nt * 16 + l15) * 8];
            acc = __builtin_amdgcn_mfma_f32_16x16x32_bf16(tf0h, w0, acc, 0, 0, 0);
            acc = __builtin_amdgcn_mfma_f32_16x16x32_bf16(tf1h, w1, acc, 0, 0, 0);
            acc = __builtin_amdgcn_mfma_f32_16x16x32_bf16(tf0l, w0, acc, 0, 0, 0);
            acc = __builtin_amdgcn_mfma_f32_16x16x32_bf16(tf1l, w1, acc, 0, 0, 0);
#pragma unroll
            for (int r = 0; r < 4; ++r)
                op[(size_t)r * EDIM + nt * 16] = acc[r] + b2v[nt];
        }
    }
    }
}

extern "C" void kernel_launch(void* const* d_in, const int* in_sizes, int n_in,
                              void* d_out, int out_size, void* d_ws, size_t ws_size,
                              hipStream_t stream) {
    const float* x   = (const float*)d_in[0];
    const float* Wi  = (const float*)d_in[2];
    const float* bi  = (const float*)d_in[3];
    const float* Wj  = (const float*)d_in[4];
    const float* bj  = (const float*)d_in[5];
    const float* lng = (const float*)d_in[6];
    const float* lnb = (const float*)d_in[7];
    const float* W1  = (const float*)d_in[8];
    const float* b1  = (const float*)d_in[9];
    const float* W2  = (const float*)d_in[10];
    const float* b2  = (const float*)d_in[11];
    float* out = (float*)d_out;

    float* NI = (float*)d_ws;
    float* NJ = NI + N_NODES * HDIM;

    proj_kernel<<<N_NODES / 4, 256, 0, stream>>>(x, Wi, bi, Wj, bj, NI, NJ);
    edge_kernel<<<2304, 256, 0, stream>>>(NI, NJ, lng, lnb, W1, b1, W2, b2, out);
}